// Round 5
// baseline (313.466 us; speedup 1.0000x reference)
//
#include <hip/hip_runtime.h>
#include <stdint.h>
#include <stddef.h>

typedef _Float16 f16;
typedef __attribute__((ext_vector_type(8))) _Float16 f16x8;
typedef __attribute__((ext_vector_type(4))) float f32x4;

#define SCHED0() __builtin_amdgcn_sched_barrier(0)

// ---------------------------------------------------------------------------
// Sparsify (2:4 soft-threshold along last dim of W[K][M]) * scale -> fp16,
// stored in MFMA-fragment order: 16B block idx =
//   ((k>>5)*(M/16) + (col>>4))*64 + ((k>>3)&3)*16 + (col&15),  elem e = k&7.
// A wave's B-fragment load = wave-uniform base + lane*16 (coalesced 1KB).
// ---------------------------------------------------------------------------
__global__ __launch_bounds__(256) void sparsify_frag(
        const float* __restrict__ W, const float* __restrict__ scale,
        f16* __restrict__ Wf, int K, int M) {
    __shared__ f16 T[64][80];
    const int r0 = blockIdx.y << 6, m0 = blockIdx.x << 6;   // r0: k-dim, m0: col
    const float s = scale[0];
    const int t = threadIdx.x;
    const int rr = t >> 2, mb = (t & 3) << 4;
    const float* src = W + (size_t)(r0 + rr) * M + m0 + mb;
    #pragma unroll
    for (int j = 0; j < 4; j++) {
        float4 v = *(const float4*)(src + j * 4);
        float a0 = fabsf(v.x), a1 = fabsf(v.y), a2 = fabsf(v.z), a3 = fabsf(v.w);
        float lo1 = fminf(a0, a1), hi1 = fmaxf(a0, a1);
        float lo2 = fminf(a2, a3), hi2 = fmaxf(a2, a3);
        float th = fminf(fmaxf(lo1, lo2), fminf(hi1, hi2));
        int m = mb + j * 4;
        T[m + 0][rr] = (f16)(copysignf(fmaxf(a0 - th, 0.f), v.x) * s);
        T[m + 1][rr] = (f16)(copysignf(fmaxf(a1 - th, 0.f), v.y) * s);
        T[m + 2][rr] = (f16)(copysignf(fmaxf(a2 - th, 0.f), v.z) * s);
        T[m + 3][rr] = (f16)(copysignf(fmaxf(a3 - th, 0.f), v.w) * s);
    }
    __syncthreads();
    const int mm = t >> 2, rb = (t & 3) << 4;
    const int col = m0 + mm;
    const int Mb = M >> 4;
    #pragma unroll
    for (int h = 0; h < 2; h++) {
        int k = r0 + rb + h * 8;
        size_t blk = ((size_t)(k >> 5) * Mb + (col >> 4)) * 64
                   + (size_t)(((k >> 3) & 3) * 16 + (col & 15));
        *(f16x8*)(Wf + blk * 8) = *(const f16x8*)&T[mm][rb + h * 8];
    }
}

#define MFMA16(a, b, c) __builtin_amdgcn_mfma_f32_16x16x32_f16((a), (b), (c), 0, 0, 0)

// ---------------------------------------------------------------------------
// GEMM1: Hf = fp16(x[16384][2048]) @ W1f + b1   (Hf in fragment order)
// BM=64 BN=64 BK=64, 256 thr (2x2 waves of 32x32), 1024 blocks = 4/CU,
// XCD-paired col-blocks (x panel L2-local).
// PIPELINE: tile t+1's global loads (A f32 regs + B fragment regs) are issued
// BEFORE compute(t); barriers are raw s_barrier with lgkmcnt(0)-only drain,
// so prefetch loads stay in flight across both barriers (counted vmcnt at
// next-iter first use, inserted by compiler). Single 8KB LDS buffer for the
// A f32->f16 transpose (WAR safe: reads complete before 2nd barrier).
// ---------------------------------------------------------------------------
__global__ __launch_bounds__(256, 4) void gemm1_kernel(
        const float* __restrict__ A, const f16* __restrict__ Bf,
        const float* __restrict__ bias, f16* __restrict__ Hf) {
    constexpr int K = 2048, BK = 64, NT = K / BK;
    __shared__ f16x8 Ash[512];   // 8 KB: [ks(2)][rowgrp(4)][lane(64)]

    const int tid = threadIdx.x, lane = tid & 63, wv = tid >> 6;
    const int wm = wv & 1, wn = wv >> 1;
    const int lr = lane & 15, q = lane >> 4;

    // XCD pairing: 4 col-blocks of row-panel p get ids == p (mod 8)
    const int id = blockIdx.x + (blockIdx.y << 2);
    const int xr = id & 7, xt = id >> 3;
    const int nb = xt & 3, p = xr + ((xt >> 2) << 3);
    const int row0 = p << 6, col0 = nb << 6;

    f32x4 acc[2][2] = {};

    // A: thread owns chunks tid (ks=0) and tid+256 (ks=1) of the LDS tile
    const int clr = tid & 15, cq = (tid >> 4) & 3, crg = tid >> 6;
    const float* aSrc = A + (size_t)(row0 + crg * 16 + clr) * K + cq * 8;
    // B: this wave's two n-chunks; kt-chunk stride = 16 chunks * 512 f16
    const f16* bBase = Bf + ((size_t)(col0 >> 4) + wn * 2) * 512 + lane * 8;

    // prologue: tile 0 into regs
    float4 a0 = *(const float4*)(aSrc);
    float4 a1 = *(const float4*)(aSrc + 4);
    float4 a2 = *(const float4*)(aSrc + 32);
    float4 a3 = *(const float4*)(aSrc + 36);
    f16x8 bA = *(const f16x8*)(bBase);
    f16x8 bB = *(const f16x8*)(bBase + 512);
    f16x8 bC = *(const f16x8*)(bBase + 8192);
    f16x8 bD = *(const f16x8*)(bBase + 8192 + 512);

    for (int t = 0; t < NT; ++t) {
        // convert current A regs -> f16, store to LDS (linear, conflict-free)
        f16x8 h0, h1;
        h0[0] = (f16)a0.x; h0[1] = (f16)a0.y; h0[2] = (f16)a0.z; h0[3] = (f16)a0.w;
        h0[4] = (f16)a1.x; h0[5] = (f16)a1.y; h0[6] = (f16)a1.z; h0[7] = (f16)a1.w;
        h1[0] = (f16)a2.x; h1[1] = (f16)a2.y; h1[2] = (f16)a2.z; h1[3] = (f16)a2.w;
        h1[4] = (f16)a3.x; h1[5] = (f16)a3.y; h1[6] = (f16)a3.z; h1[7] = (f16)a3.w;
        Ash[tid]       = h0;
        Ash[tid + 256] = h1;

        // prefetch tile t+1 (clamped; last iter re-loads tile NT-1, harmless)
        const int tn = (t + 1 < NT) ? t + 1 : NT - 1;
        const float* ap = aSrc + (size_t)tn * BK;
        float4 n0 = *(const float4*)(ap);
        float4 n1 = *(const float4*)(ap + 4);
        float4 n2 = *(const float4*)(ap + 32);
        float4 n3 = *(const float4*)(ap + 36);
        const f16* bp = bBase + (size_t)(2 * tn) * 8192;
        f16x8 nA = *(const f16x8*)(bp);
        f16x8 nB = *(const f16x8*)(bp + 512);
        f16x8 nC = *(const f16x8*)(bp + 8192);
        f16x8 nD = *(const f16x8*)(bp + 8192 + 512);

        SCHED0();
        asm volatile("s_waitcnt lgkmcnt(0)" ::: "memory");  // drain ds_writes only
        __builtin_amdgcn_s_barrier();
        SCHED0();

        f16x8 af00 = Ash[(wm * 2 + 0) * 64 + lane];
        f16x8 af01 = Ash[(wm * 2 + 1) * 64 + lane];
        f16x8 af10 = Ash[256 + (wm * 2 + 0) * 64 + lane];
        f16x8 af11 = Ash[256 + (wm * 2 + 1) * 64 + lane];
        acc[0][0] = MFMA16(af00, bA, acc[0][0]);
        acc[0][1] = MFMA16(af00, bB, acc[0][1]);
        acc[1][0] = MFMA16(af01, bA, acc[1][0]);
        acc[1][1] = MFMA16(af01, bB, acc[1][1]);
        acc[0][0] = MFMA16(af10, bC, acc[0][0]);
        acc[0][1] = MFMA16(af10, bD, acc[0][1]);
        acc[1][0] = MFMA16(af11, bC, acc[1][0]);
        acc[1][1] = MFMA16(af11, bD, acc[1][1]);

        SCHED0();
        __builtin_amdgcn_s_barrier();   // WAR: Ash rewritten next iter
        SCHED0();

        a0 = n0; a1 = n1; a2 = n2; a3 = n3;
        bA = nA; bB = nB; bC = nC; bD = nD;
    }

    // epilogue: write H in fragment order (gemm2's A layout, NROWS/16 = 1024)
    #pragma unroll
    for (int m = 0; m < 2; m++) {
        int r16 = (row0 + wm * 32 + m * 16) >> 4;
        #pragma unroll
        for (int n = 0; n < 2; n++) {
            int gc = col0 + wn * 32 + n * 16 + lr;
            float bv = bias[gc];
            int kt = gc >> 5, qq = (gc >> 3) & 3, e = gc & 7;
            f16* hb = Hf + ((((size_t)kt * 1024 + r16) * 4 + qq) * 16) * 8 + e;
            #pragma unroll
            for (int rr = 0; rr < 4; rr++)
                hb[(q * 4 + rr) * 8] = (f16)(acc[m][n][rr] + bv);
        }
    }
}

// ---------------------------------------------------------------------------
// GEMM2: y[16384][2048](f32) = H @ W2f + b2.
// BM=128 BN=128, 256 thr (2x2 waves of 64x64), grid 2048 blocks.
// Both operands fragment-order -> a wave's fragment IS a contiguous 1KB load:
// NO LDS, NO barriers. Pure reg-streaming, K=256 fully unrolled; compiler
// software-pipelines freely (nothing blocks load hoisting).
// XCD pairing: the 16 col-blocks of a row-panel share one XCD's L2.
// ---------------------------------------------------------------------------
__global__ __launch_bounds__(256, 4) void gemm2_kernel(
        const f16* __restrict__ Hf, const f16* __restrict__ Bf,
        const float* __restrict__ bias, float* __restrict__ Y) {
    constexpr int N = 2048;
    const int tid = threadIdx.x, lane = tid & 63, wv = tid >> 6;
    const int wm = wv & 1, wn = wv >> 1;
    const int lr = lane & 15, q = lane >> 4;

    const int id = blockIdx.x + (blockIdx.y << 4);
    const int xr = id & 7, xt = id >> 3;
    const int bx = xt & 15, by = xr + ((xt >> 4) << 3);
    const int row0 = by << 7, col0 = bx << 7;

    f32x4 acc[4][4] = {};

    const size_t r16b = (size_t)(row0 >> 4) + wm * 4;   // 4 consecutive r16
    const size_t c16b = (size_t)(col0 >> 4) + wn * 4;   // 4 consecutive c16

    #pragma unroll
    for (int kt = 0; kt < 8; kt++) {
        f16x8 af[4], bf[4];
        #pragma unroll
        for (int m = 0; m < 4; m++)
            af[m] = *(const f16x8*)(Hf + ((size_t)kt * 1024 + r16b + m) * 512
                                    + lane * 8);
        #pragma unroll
        for (int n = 0; n < 4; n++)
            bf[n] = *(const f16x8*)(Bf + ((size_t)kt * 128 + c16b + n) * 512
                                    + lane * 8);
        #pragma unroll
        for (int m = 0; m < 4; m++)
            #pragma unroll
            for (int n = 0; n < 4; n++)
                acc[m][n] = MFMA16(af[m], bf[n], acc[m][n]);
    }

    #pragma unroll
    for (int m = 0; m < 4; m++) {
        int gr0 = row0 + wm * 64 + m * 16 + q * 4;
        #pragma unroll
        for (int n = 0; n < 4; n++) {
            int gc = col0 + wn * 64 + n * 16 + lr;
            float bv = bias[gc];
            #pragma unroll
            for (int rr = 0; rr < 4; rr++)
                Y[(size_t)(gr0 + rr) * N + gc] = acc[m][n][rr] + bv;
        }
    }
}

// ---------------------------------------------------------------------------
// launch
// ---------------------------------------------------------------------------
extern "C" void kernel_launch(void* const* d_in, const int* in_sizes, int n_in,
                              void* d_out, int out_size, void* d_ws, size_t ws_size,
                              hipStream_t stream) {
    const float* x  = (const float*)d_in[0];   // [8,2048,2048]
    const float* w1 = (const float*)d_in[1];   // [2048,256]
    const float* w2 = (const float*)d_in[2];   // [256,2048]
    const float* b1 = (const float*)d_in[3];   // [256]
    const float* b2 = (const float*)d_in[4];   // [2048]
    const float* s1 = (const float*)d_in[5];   // [1]
    const float* s2 = (const float*)d_in[6];   // [1]
    float* y = (float*)d_out;                  // [8,2048,2048] fp32

    constexpr int NROWS = 8 * 2048;  // 16384
    constexpr int D = 2048, R = 256;

    char* ws = (char*)d_ws;
    f16* W1f = (f16*)ws;                   // fragment-order [64][16][4][16][8], 1 MiB
    f16* W2f = (f16*)(ws + (2u << 20));    // fragment-order [8][128][4][16][8], 1 MiB
    f16* Hf  = (f16*)(ws + (4u << 20));    // fragment-order [8][1024][4][16][8], 8 MiB

    hipLaunchKernelGGL(sparsify_frag, dim3(R / 64, D / 64), dim3(256),
                       0, stream, w1, s1, W1f, D, R);
    hipLaunchKernelGGL(sparsify_frag, dim3(D / 64, R / 64), dim3(256),
                       0, stream, w2, s2, W2f, R, D);

    // GEMM1: 4 x 256 = 1024 blocks (4/CU), XCD-paired A-panel sharing
    hipLaunchKernelGGL(gemm1_kernel, dim3(4, NROWS / 64), dim3(256),
                       0, stream, x, W1f, b1, Hf);

    // GEMM2: 16 x 128 = 2048 blocks, XCD-paired row-panel sharing
    hipLaunchKernelGGL(gemm2_kernel, dim3(D / 128, NROWS / 128), dim3(256),
                       0, stream, Hf, W2f, b2, y);
}